// Round 14
// baseline (158.636 us; speedup 1.0000x reference)
//
#include <hip/hip_runtime.h>

// SIRD RK4, round 14: time-sliced redundant waves (zero communication).
// Established: lone-wave issue cadence = 4.0 cyc/VALU-slot (R9: 3.97 clean);
// LDS producer/consumer handoff carries ~20 cyc/tstep structural surcharge
// (R11/R12/R13 all pinned at ~116 cyc/tstep). Compute is free: only 32 of
// 256 CUs were used. So: 8 phase-waves per scenario group REDUNDANTLY run
// the same serial chain; wave p emits rows t in [p*256, (p+1)*256).
//   bare phase: p*256 steps of pure RK4 (22 slots, no D/store/LDS/barrier)
//   store phase: 256 steps of RK4 + D-invariant + float2 store (~28 slots)
// Makespan = wave 7 = 1792*22 + 256*28 slots * 4 cyc ~ 78 us. States are
// bit-identical across waves (same code/constants) -> absmax unchanged.
// Grid: 256 blocks x 64 threads = 1 wave on each of the 256 CUs.
//
// State (sigma, I), sigma = c*S: d(sigma) = -c*(sigma*I), dI = fma(-gm,I,m).
// D from RK4-preserved invariant: D = fma(-kD/c, sigma, fma(-kD, I, kD*N)).

#define N_POP 1.0e7f
#define T_PTS 2048
#define PHASES 8
#define CHUNK (T_PTS / PHASES)   // 256 rows per wave

// One RK4 step (h=1), 22 VALU slots, updates SG and IV in place.
#define RK4_STEP(SG, IV)                                                     \
    do {                                                                     \
        const float m1 = (SG) * (IV);                                        \
        const float g1 = __builtin_fmaf(ngm, (IV), m1);                      \
        const float s2 = __builtin_fmaf(nch2, m1, (SG));                     \
        const float i2 = __builtin_fmaf(h2, g1, (IV));                       \
        const float m2 = s2 * i2;                                            \
        const float g2 = __builtin_fmaf(ngm, i2, m2);                        \
        const float s3 = __builtin_fmaf(nch2, m2, (SG));                     \
        const float i3 = __builtin_fmaf(h2, g2, (IV));                       \
        const float m3 = s3 * i3;                                            \
        const float g3 = __builtin_fmaf(ngm, i3, m3);                        \
        const float s4 = __builtin_fmaf(nch, m3, (SG));                      \
        const float i4 = (IV) + g3;                                          \
        const float m4 = s4 * i4;                                            \
        const float g4 = __builtin_fmaf(ngm, i4, m4);                        \
        float tm = __builtin_fmaf(2.0f, m2, m1);                             \
        tm = __builtin_fmaf(2.0f, m3, tm);                                   \
        (SG) = __builtin_fmaf(nwc, m4, __builtin_fmaf(nwc, tm, (SG)));       \
        float tg = __builtin_fmaf(2.0f, g2, g1);                             \
        tg = __builtin_fmaf(2.0f, g3, tg);                                   \
        (IV) = __builtin_fmaf(w, g4, __builtin_fmaf(w, tg, (IV)));           \
    } while (0)

__global__ __launch_bounds__(64, 1) void sird_kernel(const float* __restrict__ alpha,
                                                     float* __restrict__ out) {
    const int lane  = threadIdx.x;
    const int phase = blockIdx.x & (PHASES - 1);
    const int grp   = blockIdx.x >> 3;            // scenario group 0..31
    const int s     = grp * 64 + lane;

    const float beta  = alpha[s * 3 + 0];
    const float gamma = alpha[s * 3 + 1];
    const float mu    = alpha[s * 3 + 2];

    const float c    = beta * (1.0f / N_POP);
    const float gm   = gamma + mu;
    const float ngm  = -gm;
    const float h2   = 0.5f;                      // h/2, h = 1
    const float nch2 = -0.5f * c;                 // -c*h/2
    const float nch  = -c;                        // -c*h
    const float w    = 1.0f / 6.0f;
    const float nwc  = -c * (1.0f / 6.0f);
    const float kD   = mu / gm;                   // gamma,mu > 0 a.s.
    const float kDN  = kD * (float)N_POP;
    const float nkc  = -kD / c;
    const float nk   = -kD;

    float sg = c * (N_POP - 1.0f);                // sigma = c*S
    float I  = 1.0f;

    // ---- bare phase: advance to t = phase*CHUNK (pure RK4, nothing else)
    const int t0 = phase * CHUNK;                 // multiple of 256 -> unroll-8 exact
#pragma unroll 8
    for (int t = 0; t < t0; ++t) {
        RK4_STEP(sg, I);
    }

    // ---- store phase: emit rows t0 .. t0+255 (pre-step state = row t)
    float2* __restrict__ op = (float2*)out + (size_t)s * T_PTS + t0;
#pragma unroll 4
    for (int k = 0; k < CHUNK; ++k) {
        const float Dv = __builtin_fmaf(nkc, sg, __builtin_fmaf(nk, I, kDN));
        op[k] = make_float2(I, Dv);
        RK4_STEP(sg, I);
    }
}

extern "C" void kernel_launch(void* const* d_in, const int* in_sizes, int n_in,
                              void* d_out, int out_size, void* d_ws, size_t ws_size,
                              hipStream_t stream) {
    const float* alpha = (const float*)d_in[0];
    float* out = (float*)d_out;
    // 32 scenario groups x 8 time phases = 256 blocks of one wave each.
    sird_kernel<<<dim3(32 * PHASES), dim3(64), 0, stream>>>(alpha, out);
}

// Round 15
// 156.462 us; speedup vs baseline: 1.0139x; 1.0139x over previous
//
#include <hip/hip_runtime.h>

// SIRD RK4, round 15: depth-9 recurrence + R14 phase wrapper.
// Model (R1-R14 fit): T_step = max(4*insts, 10*depth) for a lone wave —
// dependent-edge latency ~10 cyc dominates; plateau at ~120 cyc/tstep was
// the depth-12 RK4 chain. This step works in v = c*S - gm so each stage is
// g_k = i_k*v_k; v_{k+1} = fma(nch*, g_k, fma(nch*gm, i_k, v)) — 2 levels
// per stage instead of 3. Depth 9, 25 VALU insts (exact RK4 reassociation).
//
// Wrapper: 8 redundant phase-waves per scenario group (R14; no LDS/barrier
// surcharge). Wave p: p*256 bare steps, then 256 store-steps.
// D from invariant: D = fma(-kD/c, v, fma(-kD, I, kD*(N - gm/c))).

#define N_POP 1.0e7f
#define T_PTS 2048
#define PHASES 8
#define CHUNK (T_PTS / PHASES)   // 256 rows per wave

// One RK4 step (h=1), 25 VALU slots, loop-carried depth 9. In-place on V,IV.
#define RK4_STEP(V, IV)                                                      \
    do {                                                                     \
        const float g1 = (V) * (IV);                           /* @1 */      \
        const float p1 = __builtin_fmaf(nch2gm, (IV), (V));    /* @1 */      \
        const float i2 = __builtin_fmaf(h2, g1, (IV));         /* @2 */      \
        const float v2 = __builtin_fmaf(nch2, g1, p1);         /* @2 */      \
        const float g2 = i2 * v2;                              /* @3 */      \
        const float p2 = __builtin_fmaf(nch2gm, i2, (V));      /* @3 */      \
        const float i3 = __builtin_fmaf(h2, g2, (IV));         /* @4 */      \
        const float v3 = __builtin_fmaf(nch2, g2, p2);         /* @4 */      \
        const float g3 = i3 * v3;                              /* @5 */      \
        const float p3 = __builtin_fmaf(nchgm, i3, (V));       /* @5 */      \
        const float i4 = (IV) + g3;                            /* @6 */      \
        const float v4 = __builtin_fmaf(nch, g3, p3);          /* @6 */      \
        const float g4 = i4 * v4;                              /* @7 */      \
        float bI = __builtin_fmaf(w, g1, (IV));                /* @2 */      \
        bI = __builtin_fmaf(w2, g2, bI);                       /* @4 */      \
        bI = __builtin_fmaf(w2, g3, bI);                       /* @6 */      \
        float a = __builtin_fmaf(nwc, g1, (V));                /* @2 */      \
        a = __builtin_fmaf(nwc2, g2, a);                       /* @4 */      \
        a = __builtin_fmaf(nwc2, g3, a);                       /* @6 */      \
        float si = __builtin_fmaf(2.0f, i2, (IV));             /* @3 */      \
        si = __builtin_fmaf(2.0f, i3, si);                     /* @5 */      \
        si = si + i4;                                          /* @7 */      \
        a = __builtin_fmaf(nwc, g4, a);                        /* @8 */      \
        (IV) = __builtin_fmaf(w, g4, bI);                      /* @8 */      \
        (V) = __builtin_fmaf(nwcgm, si, a);                    /* @9 */      \
    } while (0)

__global__ __launch_bounds__(64, 1) void sird_kernel(const float* __restrict__ alpha,
                                                     float* __restrict__ out) {
    const int lane  = threadIdx.x;
    const int phase = blockIdx.x & (PHASES - 1);
    const int grp   = blockIdx.x >> 3;            // scenario group 0..31
    const int s     = grp * 64 + lane;

    const float beta  = alpha[s * 3 + 0];
    const float gamma = alpha[s * 3 + 1];
    const float mu    = alpha[s * 3 + 2];

    const float c      = beta * (1.0f / N_POP);
    const float gm     = gamma + mu;
    const float h2     = 0.5f;                    // h/2, h = 1
    const float nch2   = -0.5f * c;               // -c*h/2
    const float nch    = -c;                      // -c*h
    const float nch2gm = nch2 * gm;
    const float nchgm  = nch * gm;
    const float w      = 1.0f / 6.0f;
    const float w2     = 1.0f / 3.0f;             // 2w
    const float nwc    = -c * (1.0f / 6.0f);
    const float nwc2   = -c * (1.0f / 3.0f);      // 2*nwc
    const float nwcgm  = nwc * gm;
    const float kD     = mu / gm;                 // gamma,mu > 0 a.s.
    const float nk     = -kD;
    const float nkc    = -kD / c;
    const float kDN2   = kD * ((float)N_POP - gm / c);

    float v = __builtin_fmaf(c, N_POP - 1.0f, -gm);   // v = c*S - gm
    float I = 1.0f;

    // ---- bare phase: advance to t = phase*CHUNK (pure RK4)
    const int t0 = phase * CHUNK;
#pragma unroll 8
    for (int t = 0; t < t0; ++t) {
        RK4_STEP(v, I);
    }

    // ---- store phase: emit rows t0 .. t0+255 (pre-step state = row t)
    float2* __restrict__ op = (float2*)out + (size_t)s * T_PTS + t0;
#pragma unroll 4
    for (int k = 0; k < CHUNK; ++k) {
        const float Dv = __builtin_fmaf(nkc, v, __builtin_fmaf(nk, I, kDN2));
        op[k] = make_float2(I, Dv);
        RK4_STEP(v, I);
    }
}

extern "C" void kernel_launch(void* const* d_in, const int* in_sizes, int n_in,
                              void* d_out, int out_size, void* d_ws, size_t ws_size,
                              hipStream_t stream) {
    const float* alpha = (const float*)d_in[0];
    float* out = (float*)d_out;
    // 32 scenario groups x 8 time phases = 256 blocks of one wave each.
    sird_kernel<<<dim3(32 * PHASES), dim3(64), 0, stream>>>(alpha, out);
}